// Round 2
// baseline (10162.720 us; speedup 1.0000x reference)
//
#include <hip/hip_runtime.h>

#define VD 128
#define HD 1024
#define BD 64
#define TD 256
#define NB 256

typedef __bf16 bf16;
typedef __bf16 bf16x8 __attribute__((ext_vector_type(8)));
typedef __bf16 bf16x4 __attribute__((ext_vector_type(4)));
typedef float f32x4 __attribute__((ext_vector_type(4)));

// ---- ws layout (byte offsets) ----
#define OFF_OUTS 0ull                           // bf16 [T][B][H]   33,554,432 B
#define OFF_XW   33554432ull                    // bf16 [T][B][V]    4,194,304 B
#define OFF_WA1  (OFF_XW  + 4194304ull)         // bf16 [4H][V]      1,048,576 B
#define OFF_WA2  (OFF_WA1 + 1048576ull)         // bf16 [4H][H]      8,388,608 B
#define OFF_WB1  (OFF_WA2 + 8388608ull)         // bf16 [4H][H]
#define OFF_WB2  (OFF_WB1 + 8388608ull)         // bf16 [4H][H]
#define OFF_WFC  (OFF_WB2 + 8388608ull)         // bf16 [V][H]         262,144 B
#define OFF_BUFA (OFF_WFC + 262144ull)          // bf16 [2][B][H]      262,144 B
#define OFF_BUFB (OFF_BUFA + 262144ull)
#define OFF_CAF  (OFF_BUFB + 262144ull)         // fp32 [B][H]
#define OFF_CBF  (OFF_CAF + 262144ull)

// dynamic LDS layout (bytes):
//   part  f32[8][16][65]          0 .. 33280
//   sWA1  bf16[16][136]       33280 .. 37632   (row stride 272 B, padded)
//   sWA2  bf16[16][1032]      37632 .. 70656   (row stride 2064 B, padded)
//   sWB1  bf16[16][1032]      70656 .. 103680
//   sWB2  bf16[16][1032]     103680 .. 136704
#define SMEM_BYTES 136704

struct Params {
  const bf16 *x, *WA1, *WA2, *WB1, *WB2;  // bf16 canonical (ws)
  const float *bA1, *bA2, *bB1, *bB2;     // fp32 biases (inputs)
  bf16 *bufA, *bufB, *outs;
  float *cA, *cB;
};

__device__ __forceinline__ bf16x8 ld8(const bf16* p) {
  return *reinterpret_cast<const bf16x8*>(p);
}
__device__ __forceinline__ float sigf(float x) { return 1.f / (1.f + __expf(-x)); }

// fp32 -> bf16 staging: x, WA1, WA2, WB1, WB2, Wfc. 4 elems/thread via float4.
__global__ void conv_k(const float* x, const float* WA1, const float* WA2,
                       const float* WB1, const float* WB2, const float* Wfc,
                       char* ws) {
  const size_t g4 = (size_t)blockIdx.x * 256 + threadIdx.x;
  size_t i = g4 * 4;
  const float* src;
  bf16* dst;
  size_t off;
  if (i < 2097152ull)        { src = x;   dst = (bf16*)(ws + OFF_XW);  off = i; }
  else if (i < 2621440ull)   { src = WA1; dst = (bf16*)(ws + OFF_WA1); off = i - 2097152ull; }
  else if (i < 6815744ull)   { src = WA2; dst = (bf16*)(ws + OFF_WA2); off = i - 2621440ull; }
  else if (i < 11010048ull)  { src = WB1; dst = (bf16*)(ws + OFF_WB1); off = i - 6815744ull; }
  else if (i < 15204352ull)  { src = WB2; dst = (bf16*)(ws + OFF_WB2); off = i - 11010048ull; }
  else if (i < 15335424ull)  { src = Wfc; dst = (bf16*)(ws + OFF_WFC); off = i - 15204352ull; }
  else return;
  float4 v = *reinterpret_cast<const float4*>(src + off);
  bf16x4 o = { (bf16)v.x, (bf16)v.y, (bf16)v.z, (bf16)v.w };
  *reinterpret_cast<bf16x4*>(dst + off) = o;
}

__global__ void init_k(const float* hA, const float* cA, const float* hB, const float* cB,
                       char* ws, unsigned* bar) {
  int i = blockIdx.x * 256 + threadIdx.x;  // 65536 = B*H
  if (i == 0) *bar = 0u;                   // reset grid barrier each replay
  ((bf16*)(ws + OFF_BUFA))[i] = (bf16)hA[i];
  ((bf16*)(ws + OFF_BUFB))[i] = (bf16)hB[i];
  ((float*)(ws + OFF_CAF))[i] = cA[i];
  ((float*)(ws + OFF_CBF))[i] = cB[i];
}

// ---------------------------------------------------------------------------
// Persistent kernel: all 257 pipeline phases in ONE plain launch.
// Co-residency by construction: 256 blocks x 136.7 KB LDS = exactly 1
// block/CU on 256 CUs, so all blocks are resident before any can finish.
// Phase t: A-step t (t<T) + B-step t-1 (t>=1). Inter-phase device coherence:
// agent-scope release fence -> monotonic counter -> spin (BOUNDED: degrades
// instead of hanging) -> agent-scope acquire fence. Stale-high counter (e.g.
// rocprof solo-replay without init_k) makes the barrier a no-op, not a hang.
// Weights: each block's 100 KB slice staged to LDS ONCE (padded row strides
// 272/2064 B -> uniform bank utilization for ds_read_b128), reused 257x.
// Math body identical to the verified phase_k.
// ---------------------------------------------------------------------------
__global__ void __launch_bounds__(512) persist_k(Params p, unsigned* bar) {
  extern __shared__ char smem[];
  float (*part)[16][65] = (float (*)[16][65])smem;
  bf16* sWA1 = (bf16*)(smem + 33280);
  bf16* sWA2 = (bf16*)(smem + 37632);
  bf16* sWB1 = (bf16*)(smem + 70656);
  bf16* sWB2 = (bf16*)(smem + 103680);

  const int tid = threadIdx.x;
  const int wv = tid >> 6, lane = tid & 63;
  const int lrow = lane & 15, q = lane >> 4;
  const int j0 = blockIdx.x * 4;
  const int cs = wv >> 2, kq = wv & 3;

  // ---- stage this block's weight slices into LDS (once) ----
  for (int i = tid; i < 256; i += 512) {        // WA1: 16 rows x 16 chunks of 8
    int r = i >> 4, c8 = (i & 15) * 8;
    int gr = (r >> 2) * HD + j0 + (r & 3);
    *(bf16x8*)(sWA1 + r * 136 + c8) = ld8(p.WA1 + (size_t)gr * VD + c8);
  }
  for (int i = tid; i < 2048; i += 512) {       // 16 rows x 128 chunks of 8
    int r = i >> 7, c8 = (i & 127) * 8;
    int gr = (r >> 2) * HD + j0 + (r & 3);
    size_t go = (size_t)gr * HD + c8;
    *(bf16x8*)(sWA2 + r * 1032 + c8) = ld8(p.WA2 + go);
    *(bf16x8*)(sWB1 + r * 1032 + c8) = ld8(p.WB1 + go);
    *(bf16x8*)(sWB2 + r * 1032 + c8) = ld8(p.WB2 + go);
  }

  // per-thread LDS read bases (B-fragment: row=lrow, col=q*8 + k)
  const bf16* lw1 = sWA1 + lrow * 136 + q * 8;
  const bf16* lw2 = sWA2 + lrow * 1032 + q * 8;
  const bf16* lwp = ((kq < 2) ? sWB1 : sWB2) + lrow * 1032 + q * 8 + (kq & 1) * 512;

  // elementwise-stage constants (hoisted out of the t-loop)
  const int eb = tid & 63;
  const int ejj = (tid >> 6) & 3;
  const int ecs = tid >> 8;
  const int ej = j0 + ejj;
  const int eidx = eb * HD + ej;
  const float* b1 = ecs ? p.bB1 : p.bA1;
  const float* b2 = ecs ? p.bB2 : p.bA2;
  float* ec = ecs ? p.cB : p.cA;
  const int wb = ecs * 4;
  float bsum[4];
#pragma unroll
  for (int g = 0; g < 4; g++) bsum[g] = b1[g * HD + ej] + b2[g * HD + ej];
  float creg = ec[eidx];   // c-state owned by this thread for the whole run

  __syncthreads();

  for (int t = 0; t <= TD; t++) {
    const bool active = (cs == 0) ? (t < TD) : (t >= 1);
    const bf16* hA = p.bufA + ((t & 1) ? (size_t)BD * HD : 0);
    if (active) {
      f32x4 acc[4] = {};
      if (cs == 0) {
        // K-chain 1152 = x(128) + hA(1024); quarter kq = [kq*288, kq*288+288)
        if (kq == 0) {
          const bf16* xb = p.x + (size_t)t * BD * VD + q * 8;
#pragma unroll
          for (int s = 0; s < 4; s++) {
            bf16x8 bfv = *(const bf16x8*)(lw1 + s * 32);
            const bf16* ap = xb + s * 32;
#pragma unroll
            for (int m = 0; m < 4; m++) {
              bf16x8 afv = ld8(ap + (m * 16 + lrow) * VD);
              acc[m] = __builtin_amdgcn_mfma_f32_16x16x32_bf16(afv, bfv, acc[m], 0, 0, 0);
            }
          }
        }
        const int hk0 = (kq == 0) ? 0 : kq * 288 - 128;
        const int nh = (kq == 0) ? 5 : 9;
#pragma unroll 3
        for (int s = 0; s < nh; s++) {
          int hk = hk0 + s * 32;
          bf16x8 bfv = *(const bf16x8*)(lw2 + hk);
          const bf16* ap = hA + hk + q * 8;
#pragma unroll
          for (int m = 0; m < 4; m++) {
            bf16x8 afv = ld8(ap + (size_t)(m * 16 + lrow) * HD);
            acc[m] = __builtin_amdgcn_mfma_f32_16x16x32_bf16(afv, bfv, acc[m], 0, 0, 0);
          }
        }
      } else {
        // K-chain 2048 = hA@WB1 (0..1023) + hB@WB2 (1024..2047); quarter = 512
        const bf16* hB = p.bufB + (((t - 1) & 1) ? (size_t)BD * HD : 0);
        const bf16* hp = (kq < 2) ? hA : hB;
        const int k0 = (kq & 1) * 512;
#pragma unroll 4
        for (int s = 0; s < 16; s++) {
          int hk = k0 + s * 32;
          bf16x8 bfv = *(const bf16x8*)(lwp + s * 32);
          const bf16* ap = hp + hk + q * 8;
#pragma unroll
          for (int m = 0; m < 4; m++) {
            bf16x8 afv = ld8(ap + (size_t)(m * 16 + lrow) * HD);
            acc[m] = __builtin_amdgcn_mfma_f32_16x16x32_bf16(afv, bfv, acc[m], 0, 0, 0);
          }
        }
      }
      // D layout: col(N)=lane&15, row(M)=q*4+r  [m89-verified]
#pragma unroll
      for (int m = 0; m < 4; m++)
#pragma unroll
        for (int r = 0; r < 4; r++)
          part[wv][lrow][m * 16 + q * 4 + r] = acc[m][r];
    }
    __syncthreads();

    // elementwise: tid 0..255 -> cell A, 256..511 -> cell B
    const bool ew = (ecs == 0) ? (t < TD) : (t >= 1);
    if (ew) {
      float g4[4];
#pragma unroll
      for (int g = 0; g < 4; g++) {
        int n = g * 4 + ejj;
        g4[g] = bsum[g] + part[wb + 0][n][eb] + part[wb + 1][n][eb] +
                part[wb + 2][n][eb] + part[wb + 3][n][eb];
      }
      float cn = sigf(g4[1]) * creg + sigf(g4[0]) * tanhf(g4[2]);
      float hn = sigf(g4[3]) * tanhf(cn);
      creg = cn;
      if (ecs == 0) {
        p.bufA[(((t + 1) & 1) ? (size_t)BD * HD : 0) + eidx] = (bf16)hn;
      } else {
        p.bufB[((t & 1) ? (size_t)BD * HD : 0) + eidx] = (bf16)hn;
        p.outs[((size_t)(t - 1) * BD + eb) * HD + ej] = (bf16)hn;
      }
    }

    // ---- grid barrier (monotonic counter, agent scope, bounded spin) ----
    if (t < TD) {
      __syncthreads();  // all LDS reads + global h writes of this block done
      if (tid == 0) {
        __threadfence();  // release: flush h writes past this XCD's L2
        __hip_atomic_fetch_add(bar, 1u, __ATOMIC_RELAXED, __HIP_MEMORY_SCOPE_AGENT);
        const unsigned tgt = (unsigned)(t + 1) * (unsigned)NB;
        int sp = 0;
        while (__hip_atomic_load(bar, __ATOMIC_RELAXED, __HIP_MEMORY_SCOPE_AGENT) < tgt) {
          __builtin_amdgcn_s_sleep(8);
          if (++sp > (1 << 17)) break;  // degrade, never hang
        }
        __threadfence();  // acquire: invalidate stale L1/L2 before next phase
      }
      __syncthreads();
    }
  }
  ec[eidx] = creg;  // final c state for tail_k
}

// Fallback single-phase kernel (used only if persist_k launch is rejected).
__global__ void __launch_bounds__(512) phase_k(Params p, int t) {
  __shared__ float part[8][16][65];
  const int tid = threadIdx.x;
  const int wv = tid >> 6, lane = tid & 63;
  const int lrow = lane & 15, q = lane >> 4;
  const int j0 = blockIdx.x * 4;
  const int cs = wv >> 2, kq = wv & 3;
  const int gate = lrow >> 2, jj = lrow & 3;
  const int grow = gate * HD + j0 + jj;

  const bf16 *w1, *w2;
  if (cs == 0) { w1 = p.WA1 + grow * VD + q * 8; w2 = p.WA2 + (size_t)grow * HD + q * 8; }
  else         { w1 = p.WB1 + (size_t)grow * HD + q * 8; w2 = p.WB2 + (size_t)grow * HD + q * 8; }

  const bool active = (cs == 0) ? (t < TD) : (t >= 1);
  const bf16* hA = p.bufA + ((t & 1) ? (size_t)BD * HD : 0);
  if (active) {
    f32x4 acc[4] = {};
    if (cs == 0) {
      if (kq == 0) {
        const bf16* xb = p.x + (size_t)t * BD * VD + q * 8;
#pragma unroll
        for (int s = 0; s < 4; s++) {
          bf16x8 bfv = ld8(w1 + s * 32);
          const bf16* ap = xb + s * 32;
#pragma unroll
          for (int m = 0; m < 4; m++) {
            bf16x8 afv = ld8(ap + (m * 16 + lrow) * VD);
            acc[m] = __builtin_amdgcn_mfma_f32_16x16x32_bf16(afv, bfv, acc[m], 0, 0, 0);
          }
        }
      }
      const int hk0 = (kq == 0) ? 0 : kq * 288 - 128;
      const int nh = (kq == 0) ? 5 : 9;
#pragma unroll 3
      for (int s = 0; s < nh; s++) {
        int hk = hk0 + s * 32;
        bf16x8 bfv = ld8(w2 + hk);
        const bf16* ap = hA + hk + q * 8;
#pragma unroll
        for (int m = 0; m < 4; m++) {
          bf16x8 afv = ld8(ap + (size_t)(m * 16 + lrow) * HD);
          acc[m] = __builtin_amdgcn_mfma_f32_16x16x32_bf16(afv, bfv, acc[m], 0, 0, 0);
        }
      }
    } else {
      const bf16* hB = p.bufB + (((t - 1) & 1) ? (size_t)BD * HD : 0);
      const bf16* hp = (kq < 2) ? hA : hB;
      const bf16* wp = (kq < 2) ? w1 : w2;
      const int k0 = (kq & 1) * 512;
#pragma unroll 4
      for (int s = 0; s < 16; s++) {
        int hk = k0 + s * 32;
        bf16x8 bfv = ld8(wp + hk);
        const bf16* ap = hp + hk + q * 8;
#pragma unroll
        for (int m = 0; m < 4; m++) {
          bf16x8 afv = ld8(ap + (size_t)(m * 16 + lrow) * HD);
          acc[m] = __builtin_amdgcn_mfma_f32_16x16x32_bf16(afv, bfv, acc[m], 0, 0, 0);
        }
      }
    }
#pragma unroll
    for (int m = 0; m < 4; m++)
#pragma unroll
      for (int r = 0; r < 4; r++)
        part[wv][lrow][m * 16 + q * 4 + r] = acc[m][r];
  }
  __syncthreads();

  const int eb = tid & 63;
  const int ejj = (tid >> 6) & 3;
  const int ecs = tid >> 8;
  const int ej = j0 + ejj;
  const int eidx = eb * HD + ej;
  const bool ew = (ecs == 0) ? (t < TD) : (t >= 1);
  if (ew) {
    const float* b1 = ecs ? p.bB1 : p.bA1;
    const float* b2 = ecs ? p.bB2 : p.bA2;
    float* ec = ecs ? p.cB : p.cA;
    const int wb = ecs * 4;
    float g4[4];
#pragma unroll
    for (int g = 0; g < 4; g++) {
      int n = g * 4 + ejj;
      g4[g] = b1[g * HD + ej] + b2[g * HD + ej] + part[wb + 0][n][eb] +
              part[wb + 1][n][eb] + part[wb + 2][n][eb] + part[wb + 3][n][eb];
    }
    float cold = ec[eidx];
    float cn = sigf(g4[1]) * cold + sigf(g4[0]) * tanhf(g4[2]);
    float hn = sigf(g4[3]) * tanhf(cn);
    ec[eidx] = cn;
    if (ecs == 0) {
      p.bufA[(((t + 1) & 1) ? (size_t)BD * HD : 0) + eidx] = (bf16)hn;
    } else {
      p.bufB[((t & 1) ? (size_t)BD * HD : 0) + eidx] = (bf16)hn;
      p.outs[((size_t)(t - 1) * BD + eb) * HD + ej] = (bf16)hn;
    }
  }
}

// out[T*B, V] = outs[T*B, H] @ Wfc[V, H]^T + bfc.  OUTPUT IS FP32.
__global__ void fc_k(const bf16* outs, const bf16* Wfc, const float* bfc, float* out) {
  const int tid = threadIdx.x;
  const int wv = tid >> 6, lane = tid & 63;
  const int lrow = lane & 15, q = lane >> 4;
  const int row0 = blockIdx.x * 64 + wv * 16;
  const bf16* arow = outs + (size_t)(row0 + lrow) * HD + q * 8;
  const bf16* wrow[8];
#pragma unroll
  for (int ct = 0; ct < 8; ct++) wrow[ct] = Wfc + (size_t)(ct * 16 + lrow) * HD + q * 8;
  f32x4 acc[8] = {};
#pragma unroll 2
  for (int s = 0; s < 32; s++) {
    bf16x8 afv = ld8(arow + s * 32);
#pragma unroll
    for (int ct = 0; ct < 8; ct++) {
      bf16x8 bfv = ld8(wrow[ct] + s * 32);
      acc[ct] = __builtin_amdgcn_mfma_f32_16x16x32_bf16(afv, bfv, acc[ct], 0, 0, 0);
    }
  }
#pragma unroll
  for (int ct = 0; ct < 8; ct++) {
    float bv = bfc[ct * 16 + lrow];
#pragma unroll
    for (int r = 0; r < 4; r++)
      out[(size_t)(row0 + q * 4 + r) * VD + ct * 16 + lrow] = acc[ct][r] + bv;
  }
}

// final states: (hA, cA, hB, cB) appended after out[T*B,V], FP32.
__global__ void tail_k(const char* ws, float* out) {
  int i = blockIdx.x * 256 + threadIdx.x;  // 65536
  float* o = out + (size_t)TD * BD * VD;
  o[i]             = (float)((const bf16*)(ws + OFF_BUFA))[i];  // hA final: parity 0
  o[65536 + i]     = ((const float*)(ws + OFF_CAF))[i];
  o[2 * 65536 + i] = (float)((const bf16*)(ws + OFF_BUFB))[i];  // hB final: parity 0
  o[3 * 65536 + i] = ((const float*)(ws + OFF_CBF))[i];
}

extern "C" void kernel_launch(void* const* d_in, const int* in_sizes, int n_in,
                              void* d_out, int out_size, void* d_ws, size_t ws_size,
                              hipStream_t stream) {
  const float* x   = (const float*)d_in[0];
  const float* hA  = (const float*)d_in[1];
  const float* cA  = (const float*)d_in[2];
  const float* hB  = (const float*)d_in[3];
  const float* cB  = (const float*)d_in[4];
  const float* WA1 = (const float*)d_in[5];
  const float* bA1 = (const float*)d_in[6];
  const float* WA2 = (const float*)d_in[7];
  const float* bA2 = (const float*)d_in[8];
  const float* WB1 = (const float*)d_in[9];
  const float* bB1 = (const float*)d_in[10];
  const float* WB2 = (const float*)d_in[11];
  const float* bB2 = (const float*)d_in[12];
  const float* Wfc = (const float*)d_in[13];
  const float* bfc = (const float*)d_in[14];

  char* ws = (char*)d_ws;
  unsigned* bar = (unsigned*)d_out;  // scratch until fc_k overwrites it

  // allow >64 KB dynamic LDS for persist_k (host-side config, once)
  static bool attr_done = false;
  if (!attr_done) {
    hipFuncSetAttribute((const void*)persist_k,
                        hipFuncAttributeMaxDynamicSharedMemorySize, SMEM_BYTES);
    attr_done = true;
  }

  conv_k<<<(15335424 / 4 + 255) / 256, 256, 0, stream>>>(x, WA1, WA2, WB1, WB2, Wfc, ws);
  init_k<<<256, 256, 0, stream>>>(hA, cA, hB, cB, ws, bar);

  Params p{(const bf16*)(ws + OFF_XW), (const bf16*)(ws + OFF_WA1),
           (const bf16*)(ws + OFF_WA2), (const bf16*)(ws + OFF_WB1),
           (const bf16*)(ws + OFF_WB2),
           bA1, bA2, bB1, bB2,
           (bf16*)(ws + OFF_BUFA), (bf16*)(ws + OFF_BUFB), (bf16*)(ws + OFF_OUTS),
           (float*)(ws + OFF_CAF), (float*)(ws + OFF_CBF)};

  // All 257 phases in one persistent kernel (plain launch; 1 block/CU by
  // LDS construction). Grid barrier replaces 257 launch/drain cycles.
  persist_k<<<NB, 512, SMEM_BYTES, stream>>>(p, bar);
  hipError_t e = hipGetLastError();
  if (e != hipSuccess) {
    // Fallback: stream-ordered phase kernels (kernel boundaries = coherence).
    for (int t = 0; t <= TD; t++) {
      phase_k<<<NB, 512, 0, stream>>>(p, t);
    }
  }

  fc_k<<<256, 256, 0, stream>>>((const bf16*)(ws + OFF_OUTS), (const bf16*)(ws + OFF_WFC),
                                bfc, (float*)d_out);
  tail_k<<<256, 256, 0, stream>>>(ws, (float*)d_out);
}

// Round 3
// 7135.117 us; speedup vs baseline: 1.4243x; 1.4243x over previous
//
#include <hip/hip_runtime.h>

#define VD 128
#define HD 1024
#define BD 64
#define TD 256
#define NB 256

typedef __bf16 bf16;
typedef __bf16 bf16x8 __attribute__((ext_vector_type(8)));
typedef __bf16 bf16x4 __attribute__((ext_vector_type(4)));
typedef float f32x4 __attribute__((ext_vector_type(4)));

// ---- ws layout (byte offsets) ----
#define OFF_OUTS 0ull                           // bf16 [T][B][H]   33,554,432 B
#define OFF_XW   33554432ull                    // bf16 [T][B][V]    4,194,304 B
#define OFF_WA1  (OFF_XW  + 4194304ull)         // bf16 [4H][V]      1,048,576 B
#define OFF_WA2  (OFF_WA1 + 1048576ull)         // bf16 [4H][H]      8,388,608 B
#define OFF_WB1  (OFF_WA2 + 8388608ull)         // bf16 [4H][H]
#define OFF_WB2  (OFF_WB1 + 8388608ull)         // bf16 [4H][H]
#define OFF_WFC  (OFF_WB2 + 8388608ull)         // bf16 [V][H]         262,144 B
#define OFF_BUFA (OFF_WFC + 262144ull)          // bf16 [2][B][H]      262,144 B
#define OFF_BUFB (OFF_BUFA + 262144ull)
#define OFF_CAF  (OFF_BUFB + 262144ull)         // fp32 [B][H]
#define OFF_CBF  (OFF_CAF + 262144ull)

// dynamic LDS layout (bytes):
//   part  f32[8][16][65]          0 .. 33280
//   sWA1  bf16[16][136]       33280 .. 37632   (row stride 272 B, padded)
//   sWA2  bf16[16][1032]      37632 .. 70656   (row stride 2064 B, padded)
//   sWB1  bf16[16][1032]      70656 .. 103680
//   sWB2  bf16[16][1032]     103680 .. 136704
#define SMEM_BYTES 136704

// barrier layout in d_out (unsigned words), all monotonic, zeroed by init_k:
//   flag     = bar[0]
//   root     = bar[32]
//   group[g] = bar[64 + 64*g], g = 0..15   (256-B spacing -> distinct lines)
#define BAR_WORDS 2048

struct Params {
  const bf16 *x, *WA1, *WA2, *WB1, *WB2;  // bf16 canonical (ws)
  const float *bA1, *bA2, *bB1, *bB2;     // fp32 biases (inputs)
  bf16 *bufA, *bufB, *outs;
  float *cA, *cB;
};

__device__ __forceinline__ bf16x8 ld8(const bf16* p) {
  return *reinterpret_cast<const bf16x8*>(p);
}
__device__ __forceinline__ float sigf(float x) { return 1.f / (1.f + __expf(-x)); }

// fp32 -> bf16 staging: x, WA1, WA2, WB1, WB2, Wfc. 4 elems/thread via float4.
__global__ void conv_k(const float* x, const float* WA1, const float* WA2,
                       const float* WB1, const float* WB2, const float* Wfc,
                       char* ws) {
  const size_t g4 = (size_t)blockIdx.x * 256 + threadIdx.x;
  size_t i = g4 * 4;
  const float* src;
  bf16* dst;
  size_t off;
  if (i < 2097152ull)        { src = x;   dst = (bf16*)(ws + OFF_XW);  off = i; }
  else if (i < 2621440ull)   { src = WA1; dst = (bf16*)(ws + OFF_WA1); off = i - 2097152ull; }
  else if (i < 6815744ull)   { src = WA2; dst = (bf16*)(ws + OFF_WA2); off = i - 2621440ull; }
  else if (i < 11010048ull)  { src = WB1; dst = (bf16*)(ws + OFF_WB1); off = i - 6815744ull; }
  else if (i < 15204352ull)  { src = WB2; dst = (bf16*)(ws + OFF_WB2); off = i - 11010048ull; }
  else if (i < 15335424ull)  { src = Wfc; dst = (bf16*)(ws + OFF_WFC); off = i - 15204352ull; }
  else return;
  float4 v = *reinterpret_cast<const float4*>(src + off);
  bf16x4 o = { (bf16)v.x, (bf16)v.y, (bf16)v.z, (bf16)v.w };
  *reinterpret_cast<bf16x4*>(dst + off) = o;
}

__global__ void init_k(const float* hA, const float* cA, const float* hB, const float* cB,
                       char* ws, unsigned* bar) {
  int i = blockIdx.x * 256 + threadIdx.x;  // 65536 = B*H
  if (i < BAR_WORDS) bar[i] = 0u;          // reset all barrier counters each replay
  ((bf16*)(ws + OFF_BUFA))[i] = (bf16)hA[i];
  ((bf16*)(ws + OFF_BUFB))[i] = (bf16)hB[i];
  ((float*)(ws + OFF_CAF))[i] = cA[i];
  ((float*)(ws + OFF_CBF))[i] = cB[i];
}

// ---------------------------------------------------------------------------
// Persistent kernel: all 257 pipeline phases in ONE plain launch.
// Co-residency by construction: 256 blocks x 136.7 KB LDS = exactly 1
// block/CU on 256 CUs, so all blocks are resident before any can finish.
// Phase t: A-step t (t<T) + B-step t-1 (t>=1).
// Inter-phase coherence: release fence -> HIERARCHICAL arrival (16 groups of
// 16 on separate lines -> root -> single flag) -> bounded flag spin ->
// acquire fence. R2 post-mortem: flat 256-RMW-one-line arrival serialized at
// ~150ns/RMW = 38us/phase (measured 39). Tree cuts arrival to ~16 serialized
// RMWs per line, groups in parallel. All counters monotonic: no resets, a
// stale-high flag (rocprof solo-replay) = no-op, never a hang.
// Weights: block's 100 KB slice staged to LDS once (padded rows), reused 257x.
// Math body identical to the verified phase_k.
// ---------------------------------------------------------------------------
__global__ void __launch_bounds__(512) persist_k(Params p, unsigned* bar) {
  extern __shared__ char smem[];
  float (*part)[16][65] = (float (*)[16][65])smem;
  bf16* sWA1 = (bf16*)(smem + 33280);
  bf16* sWA2 = (bf16*)(smem + 37632);
  bf16* sWB1 = (bf16*)(smem + 70656);
  bf16* sWB2 = (bf16*)(smem + 103680);

  const int tid = threadIdx.x;
  const int wv = tid >> 6, lane = tid & 63;
  const int lrow = lane & 15, q = lane >> 4;
  const int j0 = blockIdx.x * 4;
  const int cs = wv >> 2, kq = wv & 3;

  // ---- stage this block's weight slices into LDS (once) ----
  for (int i = tid; i < 256; i += 512) {        // WA1: 16 rows x 16 chunks of 8
    int r = i >> 4, c8 = (i & 15) * 8;
    int gr = (r >> 2) * HD + j0 + (r & 3);
    *(bf16x8*)(sWA1 + r * 136 + c8) = ld8(p.WA1 + (size_t)gr * VD + c8);
  }
  for (int i = tid; i < 2048; i += 512) {       // 16 rows x 128 chunks of 8
    int r = i >> 7, c8 = (i & 127) * 8;
    int gr = (r >> 2) * HD + j0 + (r & 3);
    size_t go = (size_t)gr * HD + c8;
    *(bf16x8*)(sWA2 + r * 1032 + c8) = ld8(p.WA2 + go);
    *(bf16x8*)(sWB1 + r * 1032 + c8) = ld8(p.WB1 + go);
    *(bf16x8*)(sWB2 + r * 1032 + c8) = ld8(p.WB2 + go);
  }

  // per-thread LDS read bases (B-fragment: row=lrow, col=q*8 + k)
  const bf16* lw1 = sWA1 + lrow * 136 + q * 8;
  const bf16* lw2 = sWA2 + lrow * 1032 + q * 8;
  const bf16* lwp = ((kq < 2) ? sWB1 : sWB2) + lrow * 1032 + q * 8 + (kq & 1) * 512;

  // elementwise-stage constants (hoisted out of the t-loop)
  const int eb = tid & 63;
  const int ejj = (tid >> 6) & 3;
  const int ecs = tid >> 8;
  const int ej = j0 + ejj;
  const int eidx = eb * HD + ej;
  const float* b1 = ecs ? p.bB1 : p.bA1;
  const float* b2 = ecs ? p.bB2 : p.bA2;
  float* ec = ecs ? p.cB : p.cA;
  const int wb = ecs * 4;
  float bsum[4];
#pragma unroll
  for (int g = 0; g < 4; g++) bsum[g] = b1[g * HD + ej] + b2[g * HD + ej];
  float creg = ec[eidx];   // c-state owned by this thread for the whole run

  __syncthreads();

  for (int t = 0; t <= TD; t++) {
    const bool active = (cs == 0) ? (t < TD) : (t >= 1);
    const bf16* hA = p.bufA + ((t & 1) ? (size_t)BD * HD : 0);
    if (active) {
      f32x4 acc[4] = {};
      if (cs == 0) {
        // K-chain 1152 = x(128) + hA(1024); quarter kq = [kq*288, kq*288+288)
        if (kq == 0) {
          const bf16* xb = p.x + (size_t)t * BD * VD + q * 8;
#pragma unroll
          for (int s = 0; s < 4; s++) {
            bf16x8 bfv = *(const bf16x8*)(lw1 + s * 32);
            const bf16* ap = xb + s * 32;
#pragma unroll
            for (int m = 0; m < 4; m++) {
              bf16x8 afv = ld8(ap + (m * 16 + lrow) * VD);
              acc[m] = __builtin_amdgcn_mfma_f32_16x16x32_bf16(afv, bfv, acc[m], 0, 0, 0);
            }
          }
        }
        const int hk0 = (kq == 0) ? 0 : kq * 288 - 128;
        const int nh = (kq == 0) ? 5 : 9;
#pragma unroll 3
        for (int s = 0; s < nh; s++) {
          int hk = hk0 + s * 32;
          bf16x8 bfv = *(const bf16x8*)(lw2 + hk);
          const bf16* ap = hA + hk + q * 8;
#pragma unroll
          for (int m = 0; m < 4; m++) {
            bf16x8 afv = ld8(ap + (size_t)(m * 16 + lrow) * HD);
            acc[m] = __builtin_amdgcn_mfma_f32_16x16x32_bf16(afv, bfv, acc[m], 0, 0, 0);
          }
        }
      } else {
        // K-chain 2048 = hA@WB1 (0..1023) + hB@WB2 (1024..2047); quarter = 512
        const bf16* hB = p.bufB + (((t - 1) & 1) ? (size_t)BD * HD : 0);
        const bf16* hp = (kq < 2) ? hA : hB;
        const int k0 = (kq & 1) * 512;
#pragma unroll 4
        for (int s = 0; s < 16; s++) {
          int hk = k0 + s * 32;
          bf16x8 bfv = *(const bf16x8*)(lwp + s * 32);
          const bf16* ap = hp + hk + q * 8;
#pragma unroll
          for (int m = 0; m < 4; m++) {
            bf16x8 afv = ld8(ap + (size_t)(m * 16 + lrow) * HD);
            acc[m] = __builtin_amdgcn_mfma_f32_16x16x32_bf16(afv, bfv, acc[m], 0, 0, 0);
          }
        }
      }
      // D layout: col(N)=lane&15, row(M)=q*4+r  [m89-verified]
#pragma unroll
      for (int m = 0; m < 4; m++)
#pragma unroll
        for (int r = 0; r < 4; r++)
          part[wv][lrow][m * 16 + q * 4 + r] = acc[m][r];
    }
    __syncthreads();

    // elementwise: tid 0..255 -> cell A, 256..511 -> cell B
    const bool ew = (ecs == 0) ? (t < TD) : (t >= 1);
    if (ew) {
      float g4[4];
#pragma unroll
      for (int g = 0; g < 4; g++) {
        int n = g * 4 + ejj;
        g4[g] = bsum[g] + part[wb + 0][n][eb] + part[wb + 1][n][eb] +
                part[wb + 2][n][eb] + part[wb + 3][n][eb];
      }
      float cn = sigf(g4[1]) * creg + sigf(g4[0]) * tanhf(g4[2]);
      float hn = sigf(g4[3]) * tanhf(cn);
      creg = cn;
      if (ecs == 0) {
        p.bufA[(((t + 1) & 1) ? (size_t)BD * HD : 0) + eidx] = (bf16)hn;
      } else {
        p.bufB[((t & 1) ? (size_t)BD * HD : 0) + eidx] = (bf16)hn;
        p.outs[((size_t)(t - 1) * BD + eb) * HD + ej] = (bf16)hn;
      }
    }

    // ---- hierarchical grid barrier (monotonic, bounded spin) ----
    if (t < TD) {
      __syncthreads();  // drains vmcnt: all global h writes of this block in L2
      if (tid == 0) {
        __threadfence();  // release: flush this XCD's L2 to coherence point
        const unsigned g = (unsigned)blockIdx.x >> 4;  // 16 groups of 16
        unsigned r = __hip_atomic_fetch_add(&bar[64 + 64 * g], 1u,
                                            __ATOMIC_RELAXED, __HIP_MEMORY_SCOPE_AGENT);
        if ((r & 15u) == 15u) {  // 16th arrival in this group this phase
          unsigned r2 = __hip_atomic_fetch_add(&bar[32], 1u,
                                               __ATOMIC_RELAXED, __HIP_MEMORY_SCOPE_AGENT);
          if ((r2 & 15u) == 15u) {  // 16th group -> all 256 blocks arrived
            __hip_atomic_store(&bar[0], (unsigned)(t + 1),
                               __ATOMIC_RELAXED, __HIP_MEMORY_SCOPE_AGENT);
          }
        }
        int sp = 0;
        while (__hip_atomic_load(&bar[0], __ATOMIC_RELAXED,
                                 __HIP_MEMORY_SCOPE_AGENT) < (unsigned)(t + 1)) {
          __builtin_amdgcn_s_sleep(2);
          if (++sp > (1 << 18)) break;  // degrade, never hang
        }
        __threadfence();  // acquire: invalidate stale L1/L2 before next phase
      }
      __syncthreads();
    }
  }
  ec[eidx] = creg;  // final c state for tail_k
}

// Fallback single-phase kernel (used only if persist_k launch is rejected).
__global__ void __launch_bounds__(512) phase_k(Params p, int t) {
  __shared__ float part[8][16][65];
  const int tid = threadIdx.x;
  const int wv = tid >> 6, lane = tid & 63;
  const int lrow = lane & 15, q = lane >> 4;
  const int j0 = blockIdx.x * 4;
  const int cs = wv >> 2, kq = wv & 3;
  const int gate = lrow >> 2, jj = lrow & 3;
  const int grow = gate * HD + j0 + jj;

  const bf16 *w1, *w2;
  if (cs == 0) { w1 = p.WA1 + grow * VD + q * 8; w2 = p.WA2 + (size_t)grow * HD + q * 8; }
  else         { w1 = p.WB1 + (size_t)grow * HD + q * 8; w2 = p.WB2 + (size_t)grow * HD + q * 8; }

  const bool active = (cs == 0) ? (t < TD) : (t >= 1);
  const bf16* hA = p.bufA + ((t & 1) ? (size_t)BD * HD : 0);
  if (active) {
    f32x4 acc[4] = {};
    if (cs == 0) {
      if (kq == 0) {
        const bf16* xb = p.x + (size_t)t * BD * VD + q * 8;
#pragma unroll
        for (int s = 0; s < 4; s++) {
          bf16x8 bfv = ld8(w1 + s * 32);
          const bf16* ap = xb + s * 32;
#pragma unroll
          for (int m = 0; m < 4; m++) {
            bf16x8 afv = ld8(ap + (m * 16 + lrow) * VD);
            acc[m] = __builtin_amdgcn_mfma_f32_16x16x32_bf16(afv, bfv, acc[m], 0, 0, 0);
          }
        }
      }
      const int hk0 = (kq == 0) ? 0 : kq * 288 - 128;
      const int nh = (kq == 0) ? 5 : 9;
#pragma unroll 3
      for (int s = 0; s < nh; s++) {
        int hk = hk0 + s * 32;
        bf16x8 bfv = ld8(w2 + hk);
        const bf16* ap = hA + hk + q * 8;
#pragma unroll
        for (int m = 0; m < 4; m++) {
          bf16x8 afv = ld8(ap + (size_t)(m * 16 + lrow) * HD);
          acc[m] = __builtin_amdgcn_mfma_f32_16x16x32_bf16(afv, bfv, acc[m], 0, 0, 0);
        }
      }
    } else {
      const bf16* hB = p.bufB + (((t - 1) & 1) ? (size_t)BD * HD : 0);
      const bf16* hp = (kq < 2) ? hA : hB;
      const bf16* wp = (kq < 2) ? w1 : w2;
      const int k0 = (kq & 1) * 512;
#pragma unroll 4
      for (int s = 0; s < 16; s++) {
        int hk = k0 + s * 32;
        bf16x8 bfv = ld8(wp + hk);
        const bf16* ap = hp + hk + q * 8;
#pragma unroll
        for (int m = 0; m < 4; m++) {
          bf16x8 afv = ld8(ap + (size_t)(m * 16 + lrow) * HD);
          acc[m] = __builtin_amdgcn_mfma_f32_16x16x32_bf16(afv, bfv, acc[m], 0, 0, 0);
        }
      }
    }
#pragma unroll
    for (int m = 0; m < 4; m++)
#pragma unroll
      for (int r = 0; r < 4; r++)
        part[wv][lrow][m * 16 + q * 4 + r] = acc[m][r];
  }
  __syncthreads();

  const int eb = tid & 63;
  const int ejj = (tid >> 6) & 3;
  const int ecs = tid >> 8;
  const int ej = j0 + ejj;
  const int eidx = eb * HD + ej;
  const bool ew = (ecs == 0) ? (t < TD) : (t >= 1);
  if (ew) {
    const float* b1 = ecs ? p.bB1 : p.bA1;
    const float* b2 = ecs ? p.bB2 : p.bA2;
    float* ec = ecs ? p.cB : p.cA;
    const int wb = ecs * 4;
    float g4[4];
#pragma unroll
    for (int g = 0; g < 4; g++) {
      int n = g * 4 + ejj;
      g4[g] = b1[g * HD + ej] + b2[g * HD + ej] + part[wb + 0][n][eb] +
              part[wb + 1][n][eb] + part[wb + 2][n][eb] + part[wb + 3][n][eb];
    }
    float cold = ec[eidx];
    float cn = sigf(g4[1]) * cold + sigf(g4[0]) * tanhf(g4[2]);
    float hn = sigf(g4[3]) * tanhf(cn);
    ec[eidx] = cn;
    if (ecs == 0) {
      p.bufA[(((t + 1) & 1) ? (size_t)BD * HD : 0) + eidx] = (bf16)hn;
    } else {
      p.bufB[((t & 1) ? (size_t)BD * HD : 0) + eidx] = (bf16)hn;
      p.outs[((size_t)(t - 1) * BD + eb) * HD + ej] = (bf16)hn;
    }
  }
}

// out[T*B, V] = outs[T*B, H] @ Wfc[V, H]^T + bfc.  OUTPUT IS FP32.
__global__ void fc_k(const bf16* outs, const bf16* Wfc, const float* bfc, float* out) {
  const int tid = threadIdx.x;
  const int wv = tid >> 6, lane = tid & 63;
  const int lrow = lane & 15, q = lane >> 4;
  const int row0 = blockIdx.x * 64 + wv * 16;
  const bf16* arow = outs + (size_t)(row0 + lrow) * HD + q * 8;
  const bf16* wrow[8];
#pragma unroll
  for (int ct = 0; ct < 8; ct++) wrow[ct] = Wfc + (size_t)(ct * 16 + lrow) * HD + q * 8;
  f32x4 acc[8] = {};
#pragma unroll 2
  for (int s = 0; s < 32; s++) {
    bf16x8 afv = ld8(arow + s * 32);
#pragma unroll
    for (int ct = 0; ct < 8; ct++) {
      bf16x8 bfv = ld8(wrow[ct] + s * 32);
      acc[ct] = __builtin_amdgcn_mfma_f32_16x16x32_bf16(afv, bfv, acc[ct], 0, 0, 0);
    }
  }
#pragma unroll
  for (int ct = 0; ct < 8; ct++) {
    float bv = bfc[ct * 16 + lrow];
#pragma unroll
    for (int r = 0; r < 4; r++)
      out[(size_t)(row0 + q * 4 + r) * VD + ct * 16 + lrow] = acc[ct][r] + bv;
  }
}

// final states: (hA, cA, hB, cB) appended after out[T*B,V], FP32.
__global__ void tail_k(const char* ws, float* out) {
  int i = blockIdx.x * 256 + threadIdx.x;  // 65536
  float* o = out + (size_t)TD * BD * VD;
  o[i]             = (float)((const bf16*)(ws + OFF_BUFA))[i];  // hA final: parity 0
  o[65536 + i]     = ((const float*)(ws + OFF_CAF))[i];
  o[2 * 65536 + i] = (float)((const bf16*)(ws + OFF_BUFB))[i];  // hB final: parity 0
  o[3 * 65536 + i] = ((const float*)(ws + OFF_CBF))[i];
}

extern "C" void kernel_launch(void* const* d_in, const int* in_sizes, int n_in,
                              void* d_out, int out_size, void* d_ws, size_t ws_size,
                              hipStream_t stream) {
  const float* x   = (const float*)d_in[0];
  const float* hA  = (const float*)d_in[1];
  const float* cA  = (const float*)d_in[2];
  const float* hB  = (const float*)d_in[3];
  const float* cB  = (const float*)d_in[4];
  const float* WA1 = (const float*)d_in[5];
  const float* bA1 = (const float*)d_in[6];
  const float* WA2 = (const float*)d_in[7];
  const float* bA2 = (const float*)d_in[8];
  const float* WB1 = (const float*)d_in[9];
  const float* bB1 = (const float*)d_in[10];
  const float* WB2 = (const float*)d_in[11];
  const float* bB2 = (const float*)d_in[12];
  const float* Wfc = (const float*)d_in[13];
  const float* bfc = (const float*)d_in[14];

  char* ws = (char*)d_ws;
  unsigned* bar = (unsigned*)d_out;  // scratch until fc_k overwrites it

  // allow >64 KB dynamic LDS for persist_k (host-side config, once)
  static bool attr_done = false;
  if (!attr_done) {
    hipFuncSetAttribute((const void*)persist_k,
                        hipFuncAttributeMaxDynamicSharedMemorySize, SMEM_BYTES);
    attr_done = true;
  }

  conv_k<<<(15335424 / 4 + 255) / 256, 256, 0, stream>>>(x, WA1, WA2, WB1, WB2, Wfc, ws);
  init_k<<<256, 256, 0, stream>>>(hA, cA, hB, cB, ws, bar);

  Params p{(const bf16*)(ws + OFF_XW), (const bf16*)(ws + OFF_WA1),
           (const bf16*)(ws + OFF_WA2), (const bf16*)(ws + OFF_WB1),
           (const bf16*)(ws + OFF_WB2),
           bA1, bA2, bB1, bB2,
           (bf16*)(ws + OFF_BUFA), (bf16*)(ws + OFF_BUFB), (bf16*)(ws + OFF_OUTS),
           (float*)(ws + OFF_CAF), (float*)(ws + OFF_CBF)};

  // All 257 phases in one persistent kernel (plain launch; 1 block/CU by
  // LDS construction). Hierarchical grid barrier replaces launch/drain.
  persist_k<<<NB, 512, SMEM_BYTES, stream>>>(p, bar);
  hipError_t e = hipGetLastError();
  if (e != hipSuccess) {
    // Fallback: stream-ordered phase kernels (kernel boundaries = coherence).
    for (int t = 0; t <= TD; t++) {
      phase_k<<<NB, 512, 0, stream>>>(p, t);
    }
  }

  fc_k<<<256, 256, 0, stream>>>((const bf16*)(ws + OFF_OUTS), (const bf16*)(ws + OFF_WFC),
                                bfc, (float*)d_out);
  tail_k<<<256, 256, 0, stream>>>(ws, (float*)d_out);
}

// Round 4
// 4882.815 us; speedup vs baseline: 2.0813x; 1.4613x over previous
//
#include <hip/hip_runtime.h>

#define VD 128
#define HD 1024
#define BD 64
#define TD 256
#define NB 256

typedef __bf16 bf16;
typedef __bf16 bf16x8 __attribute__((ext_vector_type(8)));
typedef __bf16 bf16x4 __attribute__((ext_vector_type(4)));
typedef float f32x4 __attribute__((ext_vector_type(4)));

// ---- ws layout (byte offsets) ----
#define OFF_OUTS 0ull                           // bf16 [T][B][H]   33,554,432 B
#define OFF_XW   33554432ull                    // bf16 [T][B][V]    4,194,304 B
#define OFF_WA1  (OFF_XW  + 4194304ull)         // bf16 [4H][V]      1,048,576 B
#define OFF_WA2  (OFF_WA1 + 1048576ull)         // bf16 [4H][H]      8,388,608 B
#define OFF_WB1  (OFF_WA2 + 8388608ull)         // bf16 [4H][H]
#define OFF_WB2  (OFF_WB1 + 8388608ull)         // bf16 [4H][H]
#define OFF_WFC  (OFF_WB2 + 8388608ull)         // bf16 [V][H]         262,144 B
#define OFF_BUFA (OFF_WFC + 262144ull)          // bf16 [2][B][H]      262,144 B
#define OFF_BUFB (OFF_BUFA + 262144ull)
#define OFF_CAF  (OFF_BUFB + 262144ull)         // fp32 [B][H]
#define OFF_CBF  (OFF_CAF + 262144ull)

// dynamic LDS layout (bytes):
//   part  f32[8][16][65]          0 .. 33280
//   sWA1  bf16[16][136]       33280 .. 37632   (row stride 272 B, padded)
//   sWA2  bf16[16][1032]      37632 .. 70656   (row stride 2064 B, padded)
//   sWB1  bf16[16][1032]      70656 .. 103680
//   sWB2  bf16[16][1032]     103680 .. 136704
#define SMEM_BYTES 136704

// barrier layout in d_out (unsigned words), all monotonic, zeroed by init_k:
//   flag      = bar[0]
//   slot[bid] = bar[256 + bid]   (plain stores, no RMW contention)
#define BAR_WORDS 2048

struct Params {
  const bf16 *x, *WA1, *WA2, *WB1, *WB2;  // bf16 canonical (ws)
  const float *bA1, *bA2, *bB1, *bB2;     // fp32 biases (inputs)
  bf16 *bufA, *bufB, *outs;
  float *cA, *cB;
};

__device__ __forceinline__ bf16x8 ld8(const bf16* p) {
  return *reinterpret_cast<const bf16x8*>(p);
}
__device__ __forceinline__ float sigf(float x) { return 1.f / (1.f + __expf(-x)); }

// device-scope (write-through to coherence point) bf16 store: keeps L2 clean
// so buffer_inv can never discard kernel data.
__device__ __forceinline__ void st_dev_bf16(bf16* p, float f) {
  unsigned v = (unsigned)__builtin_bit_cast(unsigned short, (bf16)f);
  asm volatile("global_store_short %0, %1, off sc0 sc1" :: "v"(p), "v"(v) : "memory");
}

// fp32 -> bf16 staging: x, WA1, WA2, WB1, WB2, Wfc. 4 elems/thread via float4.
__global__ void conv_k(const float* x, const float* WA1, const float* WA2,
                       const float* WB1, const float* WB2, const float* Wfc,
                       char* ws) {
  const size_t g4 = (size_t)blockIdx.x * 256 + threadIdx.x;
  size_t i = g4 * 4;
  const float* src;
  bf16* dst;
  size_t off;
  if (i < 2097152ull)        { src = x;   dst = (bf16*)(ws + OFF_XW);  off = i; }
  else if (i < 2621440ull)   { src = WA1; dst = (bf16*)(ws + OFF_WA1); off = i - 2097152ull; }
  else if (i < 6815744ull)   { src = WA2; dst = (bf16*)(ws + OFF_WA2); off = i - 2621440ull; }
  else if (i < 11010048ull)  { src = WB1; dst = (bf16*)(ws + OFF_WB1); off = i - 6815744ull; }
  else if (i < 15204352ull)  { src = WB2; dst = (bf16*)(ws + OFF_WB2); off = i - 11010048ull; }
  else if (i < 15335424ull)  { src = Wfc; dst = (bf16*)(ws + OFF_WFC); off = i - 15204352ull; }
  else return;
  float4 v = *reinterpret_cast<const float4*>(src + off);
  bf16x4 o = { (bf16)v.x, (bf16)v.y, (bf16)v.z, (bf16)v.w };
  *reinterpret_cast<bf16x4*>(dst + off) = o;
}

__global__ void init_k(const float* hA, const float* cA, const float* hB, const float* cB,
                       char* ws, unsigned* bar) {
  int i = blockIdx.x * 256 + threadIdx.x;  // 65536 = B*H
  if (i < BAR_WORDS) bar[i] = 0u;          // reset flag+slots each replay
  ((bf16*)(ws + OFF_BUFA))[i] = (bf16)hA[i];
  ((bf16*)(ws + OFF_BUFB))[i] = (bf16)hB[i];
  ((float*)(ws + OFF_CAF))[i] = cA[i];
  ((float*)(ws + OFF_CBF))[i] = cB[i];
}

// ---------------------------------------------------------------------------
// Persistent kernel: all 257 pipeline phases in ONE plain launch.
// Co-residency by construction: 256 blocks x 136.7 KB LDS = 1 block/CU.
// Phase t: A-step t (t<T) + B-step t-1 (t>=1).
// Coherence protocol (R3 post-mortem: post-spin staggered buffer_inv nuked
// each XCD's L2 refill all phase -> everything L3-served, ~20us/phase):
//   * h/outs stores are device-scope write-through (sc0 sc1): L2 never dirty.
//   * acquire fence (buffer_inv, no wb) runs ONCE per block BEFORE arrival:
//     all invs complete before the flag, so next phase refills L2 once per
//     XCD and then HITS. Straggler reads surviving an inv refetch identical
//     values from L3 (parity buffers) - safe.
//   * arrival = plain device-scope slot[bid] stores (no RMW serialization);
//     block 0's wave 0 sweeps 256 slots (4/lane) and publishes the flag.
// All counters monotonic; bounded spins: degrades, never hangs.
// Weights: block's 100 KB slice staged to LDS once (padded rows), reused 257x.
// Math body identical to the verified phase_k.
// ---------------------------------------------------------------------------
__global__ void __launch_bounds__(512) persist_k(Params p, unsigned* bar) {
  extern __shared__ char smem[];
  float (*part)[16][65] = (float (*)[16][65])smem;
  bf16* sWA1 = (bf16*)(smem + 33280);
  bf16* sWA2 = (bf16*)(smem + 37632);
  bf16* sWB1 = (bf16*)(smem + 70656);
  bf16* sWB2 = (bf16*)(smem + 103680);

  const int tid = threadIdx.x;
  const int wv = tid >> 6, lane = tid & 63;
  const int lrow = lane & 15, q = lane >> 4;
  const int j0 = blockIdx.x * 4;
  const int cs = wv >> 2, kq = wv & 3;

  // ---- stage this block's weight slices into LDS (once) ----
  for (int i = tid; i < 256; i += 512) {        // WA1: 16 rows x 16 chunks of 8
    int r = i >> 4, c8 = (i & 15) * 8;
    int gr = (r >> 2) * HD + j0 + (r & 3);
    *(bf16x8*)(sWA1 + r * 136 + c8) = ld8(p.WA1 + (size_t)gr * VD + c8);
  }
  for (int i = tid; i < 2048; i += 512) {       // 16 rows x 128 chunks of 8
    int r = i >> 7, c8 = (i & 127) * 8;
    int gr = (r >> 2) * HD + j0 + (r & 3);
    size_t go = (size_t)gr * HD + c8;
    *(bf16x8*)(sWA2 + r * 1032 + c8) = ld8(p.WA2 + go);
    *(bf16x8*)(sWB1 + r * 1032 + c8) = ld8(p.WB1 + go);
    *(bf16x8*)(sWB2 + r * 1032 + c8) = ld8(p.WB2 + go);
  }

  // per-thread LDS read bases (B-fragment: row=lrow, col=q*8 + k)
  const bf16* lw1 = sWA1 + lrow * 136 + q * 8;
  const bf16* lw2 = sWA2 + lrow * 1032 + q * 8;
  const bf16* lwp = ((kq < 2) ? sWB1 : sWB2) + lrow * 1032 + q * 8 + (kq & 1) * 512;

  // elementwise-stage constants (hoisted out of the t-loop)
  const int eb = tid & 63;
  const int ejj = (tid >> 6) & 3;
  const int ecs = tid >> 8;
  const int ej = j0 + ejj;
  const int eidx = eb * HD + ej;
  const float* b1 = ecs ? p.bB1 : p.bA1;
  const float* b2 = ecs ? p.bB2 : p.bA2;
  float* ec = ecs ? p.cB : p.cA;
  const int wb = ecs * 4;
  float bsum[4];
#pragma unroll
  for (int g = 0; g < 4; g++) bsum[g] = b1[g * HD + ej] + b2[g * HD + ej];
  float creg = ec[eidx];   // c-state owned by this thread for the whole run

  __syncthreads();

  for (int t = 0; t <= TD; t++) {
    const bool active = (cs == 0) ? (t < TD) : (t >= 1);
    const bf16* hA = p.bufA + ((t & 1) ? (size_t)BD * HD : 0);
    if (active) {
      f32x4 acc[4] = {};
      if (cs == 0) {
        // K-chain 1152 = x(128) + hA(1024); quarter kq = [kq*288, kq*288+288)
        if (kq == 0) {
          const bf16* xb = p.x + (size_t)t * BD * VD + q * 8;
#pragma unroll
          for (int s = 0; s < 4; s++) {
            bf16x8 bfv = *(const bf16x8*)(lw1 + s * 32);
            const bf16* ap = xb + s * 32;
#pragma unroll
            for (int m = 0; m < 4; m++) {
              bf16x8 afv = ld8(ap + (m * 16 + lrow) * VD);
              acc[m] = __builtin_amdgcn_mfma_f32_16x16x32_bf16(afv, bfv, acc[m], 0, 0, 0);
            }
          }
        }
        const int hk0 = (kq == 0) ? 0 : kq * 288 - 128;
        const int nh = (kq == 0) ? 5 : 9;
#pragma unroll 3
        for (int s = 0; s < nh; s++) {
          int hk = hk0 + s * 32;
          bf16x8 bfv = *(const bf16x8*)(lw2 + hk);
          const bf16* ap = hA + hk + q * 8;
#pragma unroll
          for (int m = 0; m < 4; m++) {
            bf16x8 afv = ld8(ap + (size_t)(m * 16 + lrow) * HD);
            acc[m] = __builtin_amdgcn_mfma_f32_16x16x32_bf16(afv, bfv, acc[m], 0, 0, 0);
          }
        }
      } else {
        // K-chain 2048 = hA@WB1 (0..1023) + hB@WB2 (1024..2047); quarter = 512
        const bf16* hB = p.bufB + (((t - 1) & 1) ? (size_t)BD * HD : 0);
        const bf16* hp = (kq < 2) ? hA : hB;
        const int k0 = (kq & 1) * 512;
#pragma unroll 4
        for (int s = 0; s < 16; s++) {
          int hk = k0 + s * 32;
          bf16x8 bfv = *(const bf16x8*)(lwp + s * 32);
          const bf16* ap = hp + hk + q * 8;
#pragma unroll
          for (int m = 0; m < 4; m++) {
            bf16x8 afv = ld8(ap + (size_t)(m * 16 + lrow) * HD);
            acc[m] = __builtin_amdgcn_mfma_f32_16x16x32_bf16(afv, bfv, acc[m], 0, 0, 0);
          }
        }
      }
      // D layout: col(N)=lane&15, row(M)=q*4+r  [m89-verified]
#pragma unroll
      for (int m = 0; m < 4; m++)
#pragma unroll
        for (int r = 0; r < 4; r++)
          part[wv][lrow][m * 16 + q * 4 + r] = acc[m][r];
    }
    __syncthreads();

    // elementwise: tid 0..255 -> cell A, 256..511 -> cell B
    const bool ew = (ecs == 0) ? (t < TD) : (t >= 1);
    if (ew) {
      float g4[4];
#pragma unroll
      for (int g = 0; g < 4; g++) {
        int n = g * 4 + ejj;
        g4[g] = bsum[g] + part[wb + 0][n][eb] + part[wb + 1][n][eb] +
                part[wb + 2][n][eb] + part[wb + 3][n][eb];
      }
      float cn = sigf(g4[1]) * creg + sigf(g4[0]) * tanhf(g4[2]);
      float hn = sigf(g4[3]) * tanhf(cn);
      creg = cn;
      if (ecs == 0) {
        st_dev_bf16(&p.bufA[(((t + 1) & 1) ? (size_t)BD * HD : 0) + eidx], hn);
      } else {
        st_dev_bf16(&p.bufB[((t & 1) ? (size_t)BD * HD : 0) + eidx], hn);
        st_dev_bf16(&p.outs[((size_t)(t - 1) * BD + eb) * HD + ej], hn);
      }
    }

    // ---- grid barrier: inv-before-arrival + slot/flag (monotonic) ----
    if (t < TD) {
      // drain sc1 stores to the coherence point before signalling arrival
      asm volatile("s_waitcnt vmcnt(0)" ::: "memory");
      __syncthreads();
      const unsigned tgt = (unsigned)(t + 1);
      if (blockIdx.x == 0 && wv == 0) {
        if (lane == 0) {
          __builtin_amdgcn_fence(__ATOMIC_ACQUIRE, "agent");  // buffer_inv (no wb)
          __hip_atomic_store(&bar[256], tgt, __ATOMIC_RELAXED, __HIP_MEMORY_SCOPE_AGENT);
        }
        // checker: 64 lanes x 4 slots per sweep
        int sp = 0;
        for (;;) {
          unsigned a0 = __hip_atomic_load(&bar[256 + lane * 4 + 0], __ATOMIC_RELAXED, __HIP_MEMORY_SCOPE_AGENT);
          unsigned a1 = __hip_atomic_load(&bar[256 + lane * 4 + 1], __ATOMIC_RELAXED, __HIP_MEMORY_SCOPE_AGENT);
          unsigned a2 = __hip_atomic_load(&bar[256 + lane * 4 + 2], __ATOMIC_RELAXED, __HIP_MEMORY_SCOPE_AGENT);
          unsigned a3 = __hip_atomic_load(&bar[256 + lane * 4 + 3], __ATOMIC_RELAXED, __HIP_MEMORY_SCOPE_AGENT);
          if (__all(a0 >= tgt && a1 >= tgt && a2 >= tgt && a3 >= tgt)) break;
          __builtin_amdgcn_s_sleep(1);
          if (++sp > (1 << 18)) break;  // degrade, never hang
        }
        if (lane == 0)
          __hip_atomic_store(&bar[0], tgt, __ATOMIC_RELAXED, __HIP_MEMORY_SCOPE_AGENT);
      } else if (tid == 0) {
        __builtin_amdgcn_fence(__ATOMIC_ACQUIRE, "agent");    // buffer_inv (no wb)
        __hip_atomic_store(&bar[256 + blockIdx.x], tgt, __ATOMIC_RELAXED, __HIP_MEMORY_SCOPE_AGENT);
        int sp = 0;
        while (__hip_atomic_load(&bar[0], __ATOMIC_RELAXED, __HIP_MEMORY_SCOPE_AGENT) < tgt) {
          __builtin_amdgcn_s_sleep(4);
          if (++sp > (1 << 18)) break;  // degrade, never hang
        }
      }
      __syncthreads();
    }
  }
  ec[eidx] = creg;  // final c state for tail_k (kernel-end release flushes)
}

// Fallback single-phase kernel (used only if persist_k launch is rejected).
__global__ void __launch_bounds__(512) phase_k(Params p, int t) {
  __shared__ float part[8][16][65];
  const int tid = threadIdx.x;
  const int wv = tid >> 6, lane = tid & 63;
  const int lrow = lane & 15, q = lane >> 4;
  const int j0 = blockIdx.x * 4;
  const int cs = wv >> 2, kq = wv & 3;
  const int gate = lrow >> 2, jj = lrow & 3;
  const int grow = gate * HD + j0 + jj;

  const bf16 *w1, *w2;
  if (cs == 0) { w1 = p.WA1 + grow * VD + q * 8; w2 = p.WA2 + (size_t)grow * HD + q * 8; }
  else         { w1 = p.WB1 + (size_t)grow * HD + q * 8; w2 = p.WB2 + (size_t)grow * HD + q * 8; }

  const bool active = (cs == 0) ? (t < TD) : (t >= 1);
  const bf16* hA = p.bufA + ((t & 1) ? (size_t)BD * HD : 0);
  if (active) {
    f32x4 acc[4] = {};
    if (cs == 0) {
      if (kq == 0) {
        const bf16* xb = p.x + (size_t)t * BD * VD + q * 8;
#pragma unroll
        for (int s = 0; s < 4; s++) {
          bf16x8 bfv = ld8(w1 + s * 32);
          const bf16* ap = xb + s * 32;
#pragma unroll
          for (int m = 0; m < 4; m++) {
            bf16x8 afv = ld8(ap + (m * 16 + lrow) * VD);
            acc[m] = __builtin_amdgcn_mfma_f32_16x16x32_bf16(afv, bfv, acc[m], 0, 0, 0);
          }
        }
      }
      const int hk0 = (kq == 0) ? 0 : kq * 288 - 128;
      const int nh = (kq == 0) ? 5 : 9;
#pragma unroll 3
      for (int s = 0; s < nh; s++) {
        int hk = hk0 + s * 32;
        bf16x8 bfv = ld8(w2 + hk);
        const bf16* ap = hA + hk + q * 8;
#pragma unroll
        for (int m = 0; m < 4; m++) {
          bf16x8 afv = ld8(ap + (size_t)(m * 16 + lrow) * HD);
          acc[m] = __builtin_amdgcn_mfma_f32_16x16x32_bf16(afv, bfv, acc[m], 0, 0, 0);
        }
      }
    } else {
      const bf16* hB = p.bufB + (((t - 1) & 1) ? (size_t)BD * HD : 0);
      const bf16* hp = (kq < 2) ? hA : hB;
      const bf16* wp = (kq < 2) ? w1 : w2;
      const int k0 = (kq & 1) * 512;
#pragma unroll 4
      for (int s = 0; s < 16; s++) {
        int hk = k0 + s * 32;
        bf16x8 bfv = ld8(wp + hk);
        const bf16* ap = hp + hk + q * 8;
#pragma unroll
        for (int m = 0; m < 4; m++) {
          bf16x8 afv = ld8(ap + (size_t)(m * 16 + lrow) * HD);
          acc[m] = __builtin_amdgcn_mfma_f32_16x16x32_bf16(afv, bfv, acc[m], 0, 0, 0);
        }
      }
    }
#pragma unroll
    for (int m = 0; m < 4; m++)
#pragma unroll
      for (int r = 0; r < 4; r++)
        part[wv][lrow][m * 16 + q * 4 + r] = acc[m][r];
  }
  __syncthreads();

  const int eb = tid & 63;
  const int ejj = (tid >> 6) & 3;
  const int ecs = tid >> 8;
  const int ej = j0 + ejj;
  const int eidx = eb * HD + ej;
  const bool ew = (ecs == 0) ? (t < TD) : (t >= 1);
  if (ew) {
    const float* b1 = ecs ? p.bB1 : p.bA1;
    const float* b2 = ecs ? p.bB2 : p.bA2;
    float* ec = ecs ? p.cB : p.cA;
    const int wb = ecs * 4;
    float g4[4];
#pragma unroll
    for (int g = 0; g < 4; g++) {
      int n = g * 4 + ejj;
      g4[g] = b1[g * HD + ej] + b2[g * HD + ej] + part[wb + 0][n][eb] +
              part[wb + 1][n][eb] + part[wb + 2][n][eb] + part[wb + 3][n][eb];
    }
    float cold = ec[eidx];
    float cn = sigf(g4[1]) * cold + sigf(g4[0]) * tanhf(g4[2]);
    float hn = sigf(g4[3]) * tanhf(cn);
    ec[eidx] = cn;
    if (ecs == 0) {
      p.bufA[(((t + 1) & 1) ? (size_t)BD * HD : 0) + eidx] = (bf16)hn;
    } else {
      p.bufB[((t & 1) ? (size_t)BD * HD : 0) + eidx] = (bf16)hn;
      p.outs[((size_t)(t - 1) * BD + eb) * HD + ej] = (bf16)hn;
    }
  }
}

// out[T*B, V] = outs[T*B, H] @ Wfc[V, H]^T + bfc.  OUTPUT IS FP32.
__global__ void fc_k(const bf16* outs, const bf16* Wfc, const float* bfc, float* out) {
  const int tid = threadIdx.x;
  const int wv = tid >> 6, lane = tid & 63;
  const int lrow = lane & 15, q = lane >> 4;
  const int row0 = blockIdx.x * 64 + wv * 16;
  const bf16* arow = outs + (size_t)(row0 + lrow) * HD + q * 8;
  const bf16* wrow[8];
#pragma unroll
  for (int ct = 0; ct < 8; ct++) wrow[ct] = Wfc + (size_t)(ct * 16 + lrow) * HD + q * 8;
  f32x4 acc[8] = {};
#pragma unroll 2
  for (int s = 0; s < 32; s++) {
    bf16x8 afv = ld8(arow + s * 32);
#pragma unroll
    for (int ct = 0; ct < 8; ct++) {
      bf16x8 bfv = ld8(wrow[ct] + s * 32);
      acc[ct] = __builtin_amdgcn_mfma_f32_16x16x32_bf16(afv, bfv, acc[ct], 0, 0, 0);
    }
  }
#pragma unroll
  for (int ct = 0; ct < 8; ct++) {
    float bv = bfc[ct * 16 + lrow];
#pragma unroll
    for (int r = 0; r < 4; r++)
      out[(size_t)(row0 + q * 4 + r) * VD + ct * 16 + lrow] = acc[ct][r] + bv;
  }
}

// final states: (hA, cA, hB, cB) appended after out[T*B,V], FP32.
__global__ void tail_k(const char* ws, float* out) {
  int i = blockIdx.x * 256 + threadIdx.x;  // 65536
  float* o = out + (size_t)TD * BD * VD;
  o[i]             = (float)((const bf16*)(ws + OFF_BUFA))[i];  // hA final: parity 0
  o[65536 + i]     = ((const float*)(ws + OFF_CAF))[i];
  o[2 * 65536 + i] = (float)((const bf16*)(ws + OFF_BUFB))[i];  // hB final: parity 0
  o[3 * 65536 + i] = ((const float*)(ws + OFF_CBF))[i];
}

extern "C" void kernel_launch(void* const* d_in, const int* in_sizes, int n_in,
                              void* d_out, int out_size, void* d_ws, size_t ws_size,
                              hipStream_t stream) {
  const float* x   = (const float*)d_in[0];
  const float* hA  = (const float*)d_in[1];
  const float* cA  = (const float*)d_in[2];
  const float* hB  = (const float*)d_in[3];
  const float* cB  = (const float*)d_in[4];
  const float* WA1 = (const float*)d_in[5];
  const float* bA1 = (const float*)d_in[6];
  const float* WA2 = (const float*)d_in[7];
  const float* bA2 = (const float*)d_in[8];
  const float* WB1 = (const float*)d_in[9];
  const float* bB1 = (const float*)d_in[10];
  const float* WB2 = (const float*)d_in[11];
  const float* bB2 = (const float*)d_in[12];
  const float* Wfc = (const float*)d_in[13];
  const float* bfc = (const float*)d_in[14];

  char* ws = (char*)d_ws;
  unsigned* bar = (unsigned*)d_out;  // scratch until fc_k overwrites it

  // allow >64 KB dynamic LDS for persist_k (host-side config, once)
  static bool attr_done = false;
  if (!attr_done) {
    hipFuncSetAttribute((const void*)persist_k,
                        hipFuncAttributeMaxDynamicSharedMemorySize, SMEM_BYTES);
    attr_done = true;
  }

  conv_k<<<(15335424 / 4 + 255) / 256, 256, 0, stream>>>(x, WA1, WA2, WB1, WB2, Wfc, ws);
  init_k<<<256, 256, 0, stream>>>(hA, cA, hB, cB, ws, bar);

  Params p{(const bf16*)(ws + OFF_XW), (const bf16*)(ws + OFF_WA1),
           (const bf16*)(ws + OFF_WA2), (const bf16*)(ws + OFF_WB1),
           (const bf16*)(ws + OFF_WB2),
           bA1, bA2, bB1, bB2,
           (bf16*)(ws + OFF_BUFA), (bf16*)(ws + OFF_BUFB), (bf16*)(ws + OFF_OUTS),
           (float*)(ws + OFF_CAF), (float*)(ws + OFF_CBF)};

  // All 257 phases in one persistent kernel (plain launch; 1 block/CU by
  // LDS construction). Slot/flag grid barrier with pre-arrival invalidate.
  persist_k<<<NB, 512, SMEM_BYTES, stream>>>(p, bar);
  hipError_t e = hipGetLastError();
  if (e != hipSuccess) {
    // Fallback: stream-ordered phase kernels (kernel boundaries = coherence).
    for (int t = 0; t <= TD; t++) {
      phase_k<<<NB, 512, 0, stream>>>(p, t);
    }
  }

  fc_k<<<256, 256, 0, stream>>>((const bf16*)(ws + OFF_OUTS), (const bf16*)(ws + OFF_WFC),
                                bfc, (float*)d_out);
  tail_k<<<256, 256, 0, stream>>>(ws, (float*)d_out);
}

// Round 5
// 3906.326 us; speedup vs baseline: 2.6016x; 1.2500x over previous
//
#include <hip/hip_runtime.h>

#define VD 128
#define HD 1024
#define BD 64
#define TD 256
#define NB 256

typedef __bf16 bf16;
typedef __bf16 bf16x8 __attribute__((ext_vector_type(8)));
typedef __bf16 bf16x4 __attribute__((ext_vector_type(4)));
typedef float f32x4 __attribute__((ext_vector_type(4)));

// ---- ws layout (byte offsets) ----
#define OFF_OUTS 0ull                           // bf16 [T][B][H]   33,554,432 B  (= hB stream slots 0..255)
#define OFF_XW   33554432ull                    // bf16 [T][B][V]    4,194,304 B
#define OFF_WA1  (OFF_XW  + 4194304ull)         // bf16 [4H][V]      1,048,576 B
#define OFF_WA2  (OFF_WA1 + 1048576ull)         // bf16 [4H][H]      8,388,608 B
#define OFF_WB1  (OFF_WA2 + 8388608ull)         // bf16 [4H][H]
#define OFF_WB2  (OFF_WB1 + 8388608ull)         // bf16 [4H][H]
#define OFF_WFC  (OFF_WB2 + 8388608ull)         // bf16 [V][H]         262,144 B
#define OFF_BUFA (OFF_WFC + 262144ull)          // bf16 [2][B][H] (fallback parity buf)
#define OFF_BUFB (OFF_BUFA + 262144ull)         // bf16 [2][B][H] (parity buf; slot0 = hB init)
#define OFF_CAF  (OFF_BUFB + 262144ull)         // fp32 [B][H]
#define OFF_CBF  (OFF_CAF + 262144ull)
#define OFF_HAST (OFF_CBF + 262144ull)          // bf16 [257][B][H] hA stream  33,685,504 B
#define HAST_BYTES (257ull * BD * HD * 2ull)

// dynamic LDS layout (bytes):
//   part  f32[8][16][65]          0 .. 33280
//   sWA1  bf16[16][136]       33280 .. 37632   (row stride 272 B, padded)
//   sWA2  bf16[16][1032]      37632 .. 70656   (row stride 2064 B, padded)
//   sWB1  bf16[16][1032]      70656 .. 103680
//   sWB2  bf16[16][1032]     103680 .. 136704
#define SMEM_BYTES 136704

// barrier layout in d_out (unsigned words), monotonic, zeroed by init_k:
//   flag      = bar[0]
//   slot[bid] = bar[256 + bid]   (plain device-scope stores, no RMW)
#define BAR_WORDS 2048

struct Params {   // fallback phase_k
  const bf16 *x, *WA1, *WA2, *WB1, *WB2;
  const float *bA1, *bA2, *bB1, *bB2;
  bf16 *bufA, *bufB, *outs;
  float *cA, *cB;
};

struct PParams {  // persistent stream kernel
  const bf16 *x, *WA1, *WA2, *WB1, *WB2;
  const float *bA1, *bA2, *bB1, *bB2;
  const bf16 *hBinit;   // initial hB (bf16)
  bf16 *hAst, *outs;    // hA stream [257][B][H]; outs = hB stream [256][B][H]
  float *cA, *cB;
};

__device__ __forceinline__ bf16x8 ld8(const bf16* p) {
  return *reinterpret_cast<const bf16x8*>(p);
}
__device__ __forceinline__ float sigf(float x) { return 1.f / (1.f + __expf(-x)); }

// device-scope write-through bf16 store: L2 never holds kernel-dirty lines.
__device__ __forceinline__ void st_dev_bf16(bf16* p, float f) {
  unsigned v = (unsigned)__builtin_bit_cast(unsigned short, (bf16)f);
  asm volatile("global_store_short %0, %1, off sc0 sc1" :: "v"(p), "v"(v) : "memory");
}

// fp32 -> bf16 staging: x, WA1, WA2, WB1, WB2, Wfc. 4 elems/thread via float4.
__global__ void conv_k(const float* x, const float* WA1, const float* WA2,
                       const float* WB1, const float* WB2, const float* Wfc,
                       char* ws) {
  const size_t g4 = (size_t)blockIdx.x * 256 + threadIdx.x;
  size_t i = g4 * 4;
  const float* src;
  bf16* dst;
  size_t off;
  if (i < 2097152ull)        { src = x;   dst = (bf16*)(ws + OFF_XW);  off = i; }
  else if (i < 2621440ull)   { src = WA1; dst = (bf16*)(ws + OFF_WA1); off = i - 2097152ull; }
  else if (i < 6815744ull)   { src = WA2; dst = (bf16*)(ws + OFF_WA2); off = i - 2621440ull; }
  else if (i < 11010048ull)  { src = WB1; dst = (bf16*)(ws + OFF_WB1); off = i - 6815744ull; }
  else if (i < 15204352ull)  { src = WB2; dst = (bf16*)(ws + OFF_WB2); off = i - 11010048ull; }
  else if (i < 15335424ull)  { src = Wfc; dst = (bf16*)(ws + OFF_WFC); off = i - 15204352ull; }
  else return;
  float4 v = *reinterpret_cast<const float4*>(src + off);
  bf16x4 o = { (bf16)v.x, (bf16)v.y, (bf16)v.z, (bf16)v.w };
  *reinterpret_cast<bf16x4*>(dst + off) = o;
}

__global__ void init_k(const float* hA, const float* cA, const float* hB, const float* cB,
                       char* ws, unsigned* bar, int stream_mode) {
  int i = blockIdx.x * 256 + threadIdx.x;  // 65536 = B*H
  if (i < BAR_WORDS) bar[i] = 0u;          // reset flag+slots each replay
  ((bf16*)(ws + OFF_BUFA))[i] = (bf16)hA[i];   // fallback parity-0 / unused in stream
  ((bf16*)(ws + OFF_BUFB))[i] = (bf16)hB[i];   // fallback parity-0 = hB init (stream)
  ((float*)(ws + OFF_CAF))[i] = cA[i];
  ((float*)(ws + OFF_CBF))[i] = cB[i];
  if (stream_mode) ((bf16*)(ws + OFF_HAST))[i] = (bf16)hA[i];  // hA stream slot 0
}

// ---------------------------------------------------------------------------
// Persistent kernel: all 257 pipeline phases in ONE plain launch.
// Co-residency by construction: 256 blocks x 136.7 KB LDS = 1 block/CU.
// Phase t: A-step t (t<T) + B-step t-1 (t>=1).
// Coherence protocol (R4 post-mortem: whole-L2 buffer_inv forced all h reads
// to fabric ~10us/phase; scattered 2B write-through stores = 16x WRITE amp):
//   * h goes to a FRESH address each phase (hA stream slot t+1; outs is the
//     hB stream). Fresh lines can't be stale in any XCD's L2 (never read
//     before written; write-through so never dirty; dispatch-boundary acquire
//     covers graph replays). => NO fences, NO invalidate; h reads are normal
//     L2-cached: each XCD fills 272 KB once from L3, then 32 CUs hit L2.
//   * elementwise remap (ejj in lane bits) -> h stores are 4-lane 8B runs.
//   * barrier: vmcnt(0) drain -> slot[bid] store -> block0/wave0 sweeps ->
//     flag; bounded spins: degrades, never hangs. All counters monotonic.
// Weights: block's 100 KB slice staged to LDS once (padded rows), reused 257x.
// Math body identical to the verified phase_k.
// ---------------------------------------------------------------------------
__global__ void __launch_bounds__(512) persist_k(PParams p, unsigned* bar) {
  extern __shared__ char smem[];
  float (*part)[16][65] = (float (*)[16][65])smem;
  bf16* sWA1 = (bf16*)(smem + 33280);
  bf16* sWA2 = (bf16*)(smem + 37632);
  bf16* sWB1 = (bf16*)(smem + 70656);
  bf16* sWB2 = (bf16*)(smem + 103680);

  const int tid = threadIdx.x;
  const int wv = tid >> 6, lane = tid & 63;
  const int lrow = lane & 15, q = lane >> 4;
  const int j0 = blockIdx.x * 4;
  const int cs = wv >> 2, kq = wv & 3;

  // ---- stage this block's weight slices into LDS (once) ----
  for (int i = tid; i < 256; i += 512) {        // WA1: 16 rows x 16 chunks of 8
    int r = i >> 4, c8 = (i & 15) * 8;
    int gr = (r >> 2) * HD + j0 + (r & 3);
    *(bf16x8*)(sWA1 + r * 136 + c8) = ld8(p.WA1 + (size_t)gr * VD + c8);
  }
  for (int i = tid; i < 2048; i += 512) {       // 16 rows x 128 chunks of 8
    int r = i >> 7, c8 = (i & 127) * 8;
    int gr = (r >> 2) * HD + j0 + (r & 3);
    size_t go = (size_t)gr * HD + c8;
    *(bf16x8*)(sWA2 + r * 1032 + c8) = ld8(p.WA2 + go);
    *(bf16x8*)(sWB1 + r * 1032 + c8) = ld8(p.WB1 + go);
    *(bf16x8*)(sWB2 + r * 1032 + c8) = ld8(p.WB2 + go);
  }

  // per-thread LDS read bases (B-fragment: row=lrow, col=q*8 + k)
  const bf16* lw1 = sWA1 + lrow * 136 + q * 8;
  const bf16* lw2 = sWA2 + lrow * 1032 + q * 8;
  const bf16* lwp = ((kq < 2) ? sWB1 : sWB2) + lrow * 1032 + q * 8 + (kq & 1) * 512;

  // elementwise-stage constants; ejj in lane bits 0-1 => 8B-contiguous stores
  const int ejj = tid & 3;
  const int eb = (tid >> 2) & 63;
  const int ecs = tid >> 8;
  const int ej = j0 + ejj;
  const int eidx = eb * HD + ej;
  const float* b1 = ecs ? p.bB1 : p.bA1;
  const float* b2 = ecs ? p.bB2 : p.bA2;
  float* ec = ecs ? p.cB : p.cA;
  const int wb = ecs * 4;
  float bsum[4];
#pragma unroll
  for (int g = 0; g < 4; g++) bsum[g] = b1[g * HD + ej] + b2[g * HD + ej];
  float creg = ec[eidx];   // c-state owned by this thread for the whole run

  __syncthreads();

  for (int t = 0; t <= TD; t++) {
    const bool active = (cs == 0) ? (t < TD) : (t >= 1);
    const bf16* hA = p.hAst + (size_t)t * (BD * HD);  // stream slot t
    if (active) {
      f32x4 acc[4] = {};
      if (cs == 0) {
        // K-chain 1152 = x(128) + hA(1024); quarter kq = [kq*288, kq*288+288)
        if (kq == 0) {
          const bf16* xb = p.x + (size_t)t * BD * VD + q * 8;
#pragma unroll
          for (int s = 0; s < 4; s++) {
            bf16x8 bfv = *(const bf16x8*)(lw1 + s * 32);
            const bf16* ap = xb + s * 32;
#pragma unroll
            for (int m = 0; m < 4; m++) {
              bf16x8 afv = ld8(ap + (m * 16 + lrow) * VD);
              acc[m] = __builtin_amdgcn_mfma_f32_16x16x32_bf16(afv, bfv, acc[m], 0, 0, 0);
            }
          }
        }
        const int hk0 = (kq == 0) ? 0 : kq * 288 - 128;
        const int nh = (kq == 0) ? 5 : 9;
#pragma unroll 3
        for (int s = 0; s < nh; s++) {
          int hk = hk0 + s * 32;
          bf16x8 bfv = *(const bf16x8*)(lw2 + hk);
          const bf16* ap = hA + hk + q * 8;
#pragma unroll
          for (int m = 0; m < 4; m++) {
            bf16x8 afv = ld8(ap + (size_t)(m * 16 + lrow) * HD);
            acc[m] = __builtin_amdgcn_mfma_f32_16x16x32_bf16(afv, bfv, acc[m], 0, 0, 0);
          }
        }
      } else {
        // K-chain 2048 = hA@WB1 (0..1023) + hB@WB2 (1024..2047); quarter = 512
        const bf16* hB = (t == 1) ? p.hBinit : p.outs + (size_t)(t - 2) * (BD * HD);
        const bf16* hp = (kq < 2) ? hA : hB;
        const int k0 = (kq & 1) * 512;
#pragma unroll 4
        for (int s = 0; s < 16; s++) {
          int hk = k0 + s * 32;
          bf16x8 bfv = *(const bf16x8*)(lwp + s * 32);
          const bf16* ap = hp + hk + q * 8;
#pragma unroll
          for (int m = 0; m < 4; m++) {
            bf16x8 afv = ld8(ap + (size_t)(m * 16 + lrow) * HD);
            acc[m] = __builtin_amdgcn_mfma_f32_16x16x32_bf16(afv, bfv, acc[m], 0, 0, 0);
          }
        }
      }
      // D layout: col(N)=lane&15, row(M)=q*4+r  [m89-verified]
#pragma unroll
      for (int m = 0; m < 4; m++)
#pragma unroll
        for (int r = 0; r < 4; r++)
          part[wv][lrow][m * 16 + q * 4 + r] = acc[m][r];
    }
    __syncthreads();

    // elementwise: tid 0..255 -> cell A, 256..511 -> cell B
    const bool ew = (ecs == 0) ? (t < TD) : (t >= 1);
    if (ew) {
      float g4[4];
#pragma unroll
      for (int g = 0; g < 4; g++) {
        int n = g * 4 + ejj;
        g4[g] = bsum[g] + part[wb + 0][n][eb] + part[wb + 1][n][eb] +
                part[wb + 2][n][eb] + part[wb + 3][n][eb];
      }
      float cn = sigf(g4[1]) * creg + sigf(g4[0]) * tanhf(g4[2]);
      float hn = sigf(g4[3]) * tanhf(cn);
      creg = cn;
      if (ecs == 0) {
        st_dev_bf16(p.hAst + (size_t)(t + 1) * (BD * HD) + eidx, hn);  // slot t+1
      } else {
        st_dev_bf16(p.outs + ((size_t)(t - 1) * BD + eb) * HD + ej, hn);  // hB stream
      }
    }

    // ---- grid barrier: slot/flag, monotonic, NO fences needed ----
    if (t < TD) {
      asm volatile("s_waitcnt vmcnt(0)" ::: "memory");  // h stores at coherence pt
      __syncthreads();
      const unsigned tgt = (unsigned)(t + 1);
      if (blockIdx.x == 0 && wv == 0) {
        if (lane == 0)
          __hip_atomic_store(&bar[256], tgt, __ATOMIC_RELAXED, __HIP_MEMORY_SCOPE_AGENT);
        int sp = 0;
        for (;;) {
          unsigned a0 = __hip_atomic_load(&bar[256 + lane * 4 + 0], __ATOMIC_RELAXED, __HIP_MEMORY_SCOPE_AGENT);
          unsigned a1 = __hip_atomic_load(&bar[256 + lane * 4 + 1], __ATOMIC_RELAXED, __HIP_MEMORY_SCOPE_AGENT);
          unsigned a2 = __hip_atomic_load(&bar[256 + lane * 4 + 2], __ATOMIC_RELAXED, __HIP_MEMORY_SCOPE_AGENT);
          unsigned a3 = __hip_atomic_load(&bar[256 + lane * 4 + 3], __ATOMIC_RELAXED, __HIP_MEMORY_SCOPE_AGENT);
          if (__all(a0 >= tgt && a1 >= tgt && a2 >= tgt && a3 >= tgt)) break;
          __builtin_amdgcn_s_sleep(1);
          if (++sp > (1 << 18)) break;  // degrade, never hang
        }
        if (lane == 0)
          __hip_atomic_store(&bar[0], tgt, __ATOMIC_RELAXED, __HIP_MEMORY_SCOPE_AGENT);
      } else if (tid == 0) {
        __hip_atomic_store(&bar[256 + blockIdx.x], tgt, __ATOMIC_RELAXED, __HIP_MEMORY_SCOPE_AGENT);
        int sp = 0;
        while (__hip_atomic_load(&bar[0], __ATOMIC_RELAXED, __HIP_MEMORY_SCOPE_AGENT) < tgt) {
          __builtin_amdgcn_s_sleep(1);
          if (++sp > (1 << 18)) break;  // degrade, never hang
        }
      }
      __syncthreads();
    }
  }
  ec[eidx] = creg;  // final c state for tail_k (dispatch-end release flushes)
}

// Fallback single-phase kernel (used only if ws too small / launch rejected).
__global__ void __launch_bounds__(512) phase_k(Params p, int t) {
  __shared__ float part[8][16][65];
  const int tid = threadIdx.x;
  const int wv = tid >> 6, lane = tid & 63;
  const int lrow = lane & 15, q = lane >> 4;
  const int j0 = blockIdx.x * 4;
  const int cs = wv >> 2, kq = wv & 3;
  const int gate = lrow >> 2, jj = lrow & 3;
  const int grow = gate * HD + j0 + jj;

  const bf16 *w1, *w2;
  if (cs == 0) { w1 = p.WA1 + grow * VD + q * 8; w2 = p.WA2 + (size_t)grow * HD + q * 8; }
  else         { w1 = p.WB1 + (size_t)grow * HD + q * 8; w2 = p.WB2 + (size_t)grow * HD + q * 8; }

  const bool active = (cs == 0) ? (t < TD) : (t >= 1);
  const bf16* hA = p.bufA + ((t & 1) ? (size_t)BD * HD : 0);
  if (active) {
    f32x4 acc[4] = {};
    if (cs == 0) {
      if (kq == 0) {
        const bf16* xb = p.x + (size_t)t * BD * VD + q * 8;
#pragma unroll
        for (int s = 0; s < 4; s++) {
          bf16x8 bfv = ld8(w1 + s * 32);
          const bf16* ap = xb + s * 32;
#pragma unroll
          for (int m = 0; m < 4; m++) {
            bf16x8 afv = ld8(ap + (m * 16 + lrow) * VD);
            acc[m] = __builtin_amdgcn_mfma_f32_16x16x32_bf16(afv, bfv, acc[m], 0, 0, 0);
          }
        }
      }
      const int hk0 = (kq == 0) ? 0 : kq * 288 - 128;
      const int nh = (kq == 0) ? 5 : 9;
#pragma unroll 3
      for (int s = 0; s < nh; s++) {
        int hk = hk0 + s * 32;
        bf16x8 bfv = ld8(w2 + hk);
        const bf16* ap = hA + hk + q * 8;
#pragma unroll
        for (int m = 0; m < 4; m++) {
          bf16x8 afv = ld8(ap + (size_t)(m * 16 + lrow) * HD);
          acc[m] = __builtin_amdgcn_mfma_f32_16x16x32_bf16(afv, bfv, acc[m], 0, 0, 0);
        }
      }
    } else {
      const bf16* hB = p.bufB + (((t - 1) & 1) ? (size_t)BD * HD : 0);
      const bf16* hp = (kq < 2) ? hA : hB;
      const bf16* wp = (kq < 2) ? w1 : w2;
      const int k0 = (kq & 1) * 512;
#pragma unroll 4
      for (int s = 0; s < 16; s++) {
        int hk = k0 + s * 32;
        bf16x8 bfv = ld8(wp + hk);
        const bf16* ap = hp + hk + q * 8;
#pragma unroll
        for (int m = 0; m < 4; m++) {
          bf16x8 afv = ld8(ap + (size_t)(m * 16 + lrow) * HD);
          acc[m] = __builtin_amdgcn_mfma_f32_16x16x32_bf16(afv, bfv, acc[m], 0, 0, 0);
        }
      }
    }
#pragma unroll
    for (int m = 0; m < 4; m++)
#pragma unroll
      for (int r = 0; r < 4; r++)
        part[wv][lrow][m * 16 + q * 4 + r] = acc[m][r];
  }
  __syncthreads();

  const int eb = tid & 63;
  const int ejj = (tid >> 6) & 3;
  const int ecs = tid >> 8;
  const int ej = j0 + ejj;
  const int eidx = eb * HD + ej;
  const bool ew = (ecs == 0) ? (t < TD) : (t >= 1);
  if (ew) {
    const float* b1 = ecs ? p.bB1 : p.bA1;
    const float* b2 = ecs ? p.bB2 : p.bA2;
    float* ec = ecs ? p.cB : p.cA;
    const int wb = ecs * 4;
    float g4[4];
#pragma unroll
    for (int g = 0; g < 4; g++) {
      int n = g * 4 + ejj;
      g4[g] = b1[g * HD + ej] + b2[g * HD + ej] + part[wb + 0][n][eb] +
              part[wb + 1][n][eb] + part[wb + 2][n][eb] + part[wb + 3][n][eb];
    }
    float cold = ec[eidx];
    float cn = sigf(g4[1]) * cold + sigf(g4[0]) * tanhf(g4[2]);
    float hn = sigf(g4[3]) * tanhf(cn);
    ec[eidx] = cn;
    if (ecs == 0) {
      p.bufA[(((t + 1) & 1) ? (size_t)BD * HD : 0) + eidx] = (bf16)hn;
    } else {
      p.bufB[((t & 1) ? (size_t)BD * HD : 0) + eidx] = (bf16)hn;
      p.outs[((size_t)(t - 1) * BD + eb) * HD + ej] = (bf16)hn;
    }
  }
}

// out[T*B, V] = outs[T*B, H] @ Wfc[V, H]^T + bfc.  OUTPUT IS FP32.
__global__ void fc_k(const bf16* outs, const bf16* Wfc, const float* bfc, float* out) {
  const int tid = threadIdx.x;
  const int wv = tid >> 6, lane = tid & 63;
  const int lrow = lane & 15, q = lane >> 4;
  const int row0 = blockIdx.x * 64 + wv * 16;
  const bf16* arow = outs + (size_t)(row0 + lrow) * HD + q * 8;
  const bf16* wrow[8];
#pragma unroll
  for (int ct = 0; ct < 8; ct++) wrow[ct] = Wfc + (size_t)(ct * 16 + lrow) * HD + q * 8;
  f32x4 acc[8] = {};
#pragma unroll 2
  for (int s = 0; s < 32; s++) {
    bf16x8 afv = ld8(arow + s * 32);
#pragma unroll
    for (int ct = 0; ct < 8; ct++) {
      bf16x8 bfv = ld8(wrow[ct] + s * 32);
      acc[ct] = __builtin_amdgcn_mfma_f32_16x16x32_bf16(afv, bfv, acc[ct], 0, 0, 0);
    }
  }
#pragma unroll
  for (int ct = 0; ct < 8; ct++) {
    float bv = bfc[ct * 16 + lrow];
#pragma unroll
    for (int r = 0; r < 4; r++)
      out[(size_t)(row0 + q * 4 + r) * VD + ct * 16 + lrow] = acc[ct][r] + bv;
  }
}

// final states: (hA, cA, hB, cB) appended after out[T*B,V], FP32.
__global__ void tail_k(const char* ws, float* out, int stream_mode) {
  int i = blockIdx.x * 256 + threadIdx.x;  // 65536
  float* o = out + (size_t)TD * BD * VD;
  const bf16* hAf = stream_mode
      ? (const bf16*)(ws + OFF_HAST) + (size_t)TD * BD * HD   // stream slot 256
      : (const bf16*)(ws + OFF_BUFA);                          // parity 0
  const bf16* hBf = stream_mode
      ? (const bf16*)(ws + OFF_OUTS) + (size_t)(TD - 1) * BD * HD  // outs slot 255
      : (const bf16*)(ws + OFF_BUFB);                          // parity 0
  o[i]             = (float)hAf[i];
  o[65536 + i]     = ((const float*)(ws + OFF_CAF))[i];
  o[2 * 65536 + i] = (float)hBf[i];
  o[3 * 65536 + i] = ((const float*)(ws + OFF_CBF))[i];
}

extern "C" void kernel_launch(void* const* d_in, const int* in_sizes, int n_in,
                              void* d_out, int out_size, void* d_ws, size_t ws_size,
                              hipStream_t stream) {
  const float* x   = (const float*)d_in[0];
  const float* hA  = (const float*)d_in[1];
  const float* cA  = (const float*)d_in[2];
  const float* hB  = (const float*)d_in[3];
  const float* cB  = (const float*)d_in[4];
  const float* WA1 = (const float*)d_in[5];
  const float* bA1 = (const float*)d_in[6];
  const float* WA2 = (const float*)d_in[7];
  const float* bA2 = (const float*)d_in[8];
  const float* WB1 = (const float*)d_in[9];
  const float* bB1 = (const float*)d_in[10];
  const float* WB2 = (const float*)d_in[11];
  const float* bB2 = (const float*)d_in[12];
  const float* Wfc = (const float*)d_in[13];
  const float* bfc = (const float*)d_in[14];

  char* ws = (char*)d_ws;
  unsigned* bar = (unsigned*)d_out;  // scratch until fc_k overwrites it

  const int stream_mode = (ws_size >= OFF_HAST + HAST_BYTES) ? 1 : 0;

  // allow >64 KB dynamic LDS for persist_k (host-side config, once)
  static bool attr_done = false;
  if (!attr_done) {
    hipFuncSetAttribute((const void*)persist_k,
                        hipFuncAttributeMaxDynamicSharedMemorySize, SMEM_BYTES);
    attr_done = true;
  }

  conv_k<<<(15335424 / 4 + 255) / 256, 256, 0, stream>>>(x, WA1, WA2, WB1, WB2, Wfc, ws);
  init_k<<<256, 256, 0, stream>>>(hA, cA, hB, cB, ws, bar, stream_mode);

  bool used_stream = false;
  if (stream_mode) {
    PParams pp{(const bf16*)(ws + OFF_XW), (const bf16*)(ws + OFF_WA1),
               (const bf16*)(ws + OFF_WA2), (const bf16*)(ws + OFF_WB1),
               (const bf16*)(ws + OFF_WB2),
               bA1, bA2, bB1, bB2,
               (const bf16*)(ws + OFF_BUFB),           // hB init (parity slot 0)
               (bf16*)(ws + OFF_HAST), (bf16*)(ws + OFF_OUTS),
               (float*)(ws + OFF_CAF), (float*)(ws + OFF_CBF)};
    persist_k<<<NB, 512, SMEM_BYTES, stream>>>(pp, bar);
    used_stream = (hipGetLastError() == hipSuccess);
  }
  if (!used_stream) {
    Params p{(const bf16*)(ws + OFF_XW), (const bf16*)(ws + OFF_WA1),
             (const bf16*)(ws + OFF_WA2), (const bf16*)(ws + OFF_WB1),
             (const bf16*)(ws + OFF_WB2),
             bA1, bA2, bB1, bB2,
             (bf16*)(ws + OFF_BUFA), (bf16*)(ws + OFF_BUFB), (bf16*)(ws + OFF_OUTS),
             (float*)(ws + OFF_CAF), (float*)(ws + OFF_CBF)};
    for (int t = 0; t <= TD; t++) {
      phase_k<<<NB, 512, 0, stream>>>(p, t);
    }
  }

  fc_k<<<256, 256, 0, stream>>>((const bf16*)(ws + OFF_OUTS), (const bf16*)(ws + OFF_WFC),
                                bfc, (float*)d_out);
  tail_k<<<256, 256, 0, stream>>>(ws, (float*)d_out, used_stream ? 1 : 0);
}